// Round 4
// baseline (573.410 us; speedup 1.0000x reference)
//
#include <hip/hip_runtime.h>
#include <stdint.h>

// RegimePatternBank: B=32768 regime rows (D=512), P=4096 prototypes.
//  prep (x2): norms, bf16-normalized rows (regime: row-major; proto: MFMA
//             fragment-tiled [pb][kb][lane*16B]), fp32-normalized protos,
//             MLP projections rproj/cproj (layer-1 linear in the concat).
//  topk:      256 blocks x 512 thr (8 waves). Regime tile (128 rows, 128 KB)
//             loaded into LDS ONCE -> barrier-free main loop. Protos stream
//             global->register (fragment-order, coalesced dwordx4, L2/L1
//             resident). mfma_f32_32x32x16_bf16, wave tile 128p x 64r
//             (acc 4x2 f32x16 = 128 VGPR), half-phase ping-pong A prefetch.
//             In-register top-3/lane (packed f32key|col), merged lane/lane+32
//             then across 4 wp waves -> top-8/row.
//  finalize:  fp64 rescore of margin-gated candidates (4e-3 ~ 20 sigma of
//             bf16-key noise), exact top-3 (tie -> lower index), softmax(x5),
//             fused MLP via rproj/cproj.

#define BDIM 512
#define NB   32768
#define NP   4096
#define RPB  128    // regime rows per topk block

typedef float  f32x16 __attribute__((ext_vector_type(16)));
typedef short  s16x8  __attribute__((ext_vector_type(8)));
typedef unsigned short u16;

typedef const __attribute__((address_space(1))) unsigned int* gas_t;
typedef __attribute__((address_space(3))) unsigned int* las_t;

__device__ __forceinline__ void gll16(const void* g, void* l) {
  __builtin_amdgcn_global_load_lds((gas_t)g, (las_t)l, 16, 0, 0);
}

__device__ __forceinline__ u16 f2bf(float f) {
  uint32_t u = __float_as_uint(f);
  return (u16)((u + 0x7FFFu + ((u >> 16) & 1u)) >> 16);
}
__device__ __forceinline__ uint32_t umx(uint32_t a, uint32_t b) { return a > b ? a : b; }
__device__ __forceinline__ uint32_t umn(uint32_t a, uint32_t b) { return a > b ? b : a; }

// map f32 bits -> u32 with float ordering; pack top-20 value bits | 12-bit col
__device__ __forceinline__ uint32_t packkey(float v, int col) {
  uint32_t u = __float_as_uint(v);
  uint32_t mp = u ^ (uint32_t)(((int)u >> 31) | 0x80000000);
  return (mp & 0xFFFFF000u) | (uint32_t)col;
}
__device__ __forceinline__ float unpackf(uint32_t k) {
  uint32_t mbits = k & 0xFFFFF000u;
  uint32_t u = (mbits & 0x80000000u) ? (mbits ^ 0x80000000u) : ~mbits;
  return __uint_as_float(u);
}

// insert key into sorted-descending 8-list
__device__ __forceinline__ void ins8(uint32_t* t, uint32_t k) {
#pragma unroll
  for (int i = 0; i < 8; ++i) {
    uint32_t mx = umx(t[i], k), mn = umn(t[i], k);
    t[i] = mx; k = mn;
  }
}

// a,b sorted desc -> a = top-8 of union (bitonic merge network)
__device__ __forceinline__ void bmerge(uint32_t* a, const uint32_t* b) {
  uint32_t t[8];
#pragma unroll
  for (int i = 0; i < 8; ++i) t[i] = umx(a[i], b[7 - i]);
#pragma unroll
  for (int i = 0; i < 4; ++i) { uint32_t x = umx(t[i], t[i + 4]), y = umn(t[i], t[i + 4]); t[i] = x; t[i + 4] = y; }
#pragma unroll
  for (int g = 0; g < 8; g += 4)
#pragma unroll
    for (int i = 0; i < 2; ++i) { uint32_t x = umx(t[g + i], t[g + i + 2]), y = umn(t[g + i], t[g + i + 2]); t[g + i] = x; t[g + i + 2] = y; }
#pragma unroll
  for (int p = 0; p < 8; p += 2) { uint32_t x = umx(t[p], t[p + 1]), y = umn(t[p], t[p + 1]); t[p] = x; t[p + 1] = y; }
#pragma unroll
  for (int i = 0; i < 8; ++i) a[i] = t[i];
}
__device__ __forceinline__ void mergeshfl(uint32_t* a, int mask) {
  uint32_t b[8];
#pragma unroll
  for (int i = 0; i < 8; ++i) b[i] = (uint32_t)__shfl_xor((int)a[i], mask, 64);
  bmerge(a, b);
}

// ---------------------------------------------------------------------------
// prep: 16 rows/block, 256 thr. W1-half in registers (64/thread). mode 0 =
// regime (row-major bf16 + nrm); mode 1 = proto (fragment-tiled bf16
// [pb][kb][lane*16B] + fp32 normalized). Both: proj = W1[:, off:+512] @ row.
// ---------------------------------------------------------------------------
__global__ __launch_bounds__(256) void prep_kernel(
    const float* __restrict__ src, const float* __restrict__ W1, int w1_off,
    int mode, u16* __restrict__ obf, float* __restrict__ onrm,
    float* __restrict__ oproj, float* __restrict__ onf32)
{
  __shared__ float rows[16][512];     // 32 KB
  __shared__ float pscr[16][8][32];   // 16 KB
  const int t = threadIdx.x, l = t & 63, w = t >> 6;
  const long rowbase = (long)blockIdx.x * 16;

  { // stage 16 raw rows
    const int r = t >> 4, c0 = (t & 15) * 32;
    const float4* gp = (const float4*)(src + (rowbase + r) * BDIM + c0);
    float4* dp = (float4*)&rows[r][c0];
#pragma unroll
    for (int i = 0; i < 8; ++i) dp[i] = gp[i];
  }
  float wreg[64]; // thread (h=t&31, seg=t>>5) holds W1[h][w1_off+seg*64 .. +64)
  {
    const int h = t & 31, seg = t >> 5;
    const float* wp = W1 + h * 1024 + w1_off + seg * 64;
#pragma unroll
    for (int i = 0; i < 64; ++i) wreg[i] = wp[i];
  }
  __syncthreads();

  // normalize: wave w handles rows 4w..4w+3
#pragma unroll
  for (int i = 0; i < 4; ++i) {
    const int r = w * 4 + i;
    const long row = rowbase + r;
    float4 a = *(const float4*)&rows[r][4 * l];
    float4 c = *(const float4*)&rows[r][256 + 4 * l];
    float ss = a.x * a.x + a.y * a.y + a.z * a.z + a.w * a.w
             + c.x * c.x + c.y * c.y + c.z * c.z + c.w * c.w;
#pragma unroll
    for (int msk = 1; msk < 64; msk <<= 1) ss += __shfl_xor(ss, msk, 64);
    const float n = fmaxf(sqrtf(ss), 1e-12f);
    if (mode == 0) {
      if (l == 0) onrm[row] = n;
      float4 qa, qc;
      qa.x = a.x / n; qa.y = a.y / n; qa.z = a.z / n; qa.w = a.w / n;
      qc.x = c.x / n; qc.y = c.y / n; qc.z = c.z / n; qc.w = c.w / n;
      ushort4 u0, u1;
      u0.x = f2bf(qa.x); u0.y = f2bf(qa.y); u0.z = f2bf(qa.z); u0.w = f2bf(qa.w);
      u1.x = f2bf(qc.x); u1.y = f2bf(qc.y); u1.z = f2bf(qc.z); u1.w = f2bf(qc.w);
      *(ushort4*)(obf + row * BDIM + 4 * l) = u0;
      *(ushort4*)(obf + row * BDIM + 256 + 4 * l) = u1;
    } else {
      // lane's 8 contiguous elems [8l..8l+8) = tile (pb=row>>5, kb=l>>1),
      // fragment lane = (l&1)*32 + (row&31)
      const float4 s0 = *(const float4*)&rows[r][8 * l];
      const float4 s1 = *(const float4*)&rows[r][8 * l + 4];
      float4 q0, q1;
      q0.x = s0.x / n; q0.y = s0.y / n; q0.z = s0.z / n; q0.w = s0.w / n;
      q1.x = s1.x / n; q1.y = s1.y / n; q1.z = s1.z / n; q1.w = s1.w / n;
      ushort4 u0, u1;
      u0.x = f2bf(q0.x); u0.y = f2bf(q0.y); u0.z = f2bf(q0.z); u0.w = f2bf(q0.w);
      u1.x = f2bf(q1.x); u1.y = f2bf(q1.y); u1.z = f2bf(q1.z); u1.w = f2bf(q1.w);
      const int rr = (int)row;
      char* dst = (char*)obf + ((long)((rr >> 5) * 32 + (l >> 1)) * 1024)
                + ((l & 1) * 32 + (rr & 31)) * 16;
      *(ushort4*)(dst) = u0;
      *(ushort4*)(dst + 8) = u1;
      *(float4*)(onf32 + row * BDIM + 8 * l) = q0;
      *(float4*)(onf32 + row * BDIM + 8 * l + 4) = q1;
    }
  }

  // proj partials on RAW rows
  const int h = t & 31, seg = t >> 5;
  for (int r = 0; r < 16; ++r) {
    float p = 0.f;
#pragma unroll
    for (int j = 0; j < 16; ++j) {
      const float4 rv = *(const float4*)&rows[r][seg * 64 + 4 * j];
      p = fmaf(wreg[4 * j + 0], rv.x, p);
      p = fmaf(wreg[4 * j + 1], rv.y, p);
      p = fmaf(wreg[4 * j + 2], rv.z, p);
      p = fmaf(wreg[4 * j + 3], rv.w, p);
    }
    pscr[r][seg][h] = p;
  }
  __syncthreads();
#pragma unroll
  for (int q = 0; q < 2; ++q) {
    const int idx = t + q * 256;
    const int rr = idx >> 5, hh = idx & 31;
    float s = 0.f;
#pragma unroll
    for (int sg = 0; sg < 8; ++sg) s += pscr[rr][sg][hh];
    oproj[(rowbase + rr) * 32 + hh] = s;
  }
}

// ---------------------------------------------------------------------------
// topk: 256 blocks x 512 thr (8 waves = 4 wp x 2 wn). Regime (128 rows x 512k
// bf16 = 128 KB) in LDS for the whole kernel (XOR-swizzled granules).
// Protos stream global->reg in fragment order. Barrier-free main loop.
// ---------------------------------------------------------------------------
__global__ __launch_bounds__(512, 2) void topk_kernel(
    const u16* __restrict__ Rn,   // [32768][512] bf16 (row-major)
    const u16* __restrict__ Pk,   // [128 pb][32 kb][64 lanes x 16B] fragment-tiled
    uint32_t* __restrict__ keys8) // [32768][8] packed keys
{
  __shared__ uint4 lds4[9216];                 // 147456 B
  char* ldsb = (char*)lds4;                    // regime [128 rows][64 gran][16B]
  uint32_t* mrg = (uint32_t*)(ldsb + 131072);  // [128 rows][4 wp][8]

  const int t = threadIdx.x, l = t & 63, wid = t >> 6;
  const int wp = wid & 3;        // proto quarter (0..3)
  const int wn = wid >> 2;       // regime half (0..1)
  const int l5 = l >> 5;
  const long rb = (long)blockIdx.x * RPB;

  // ---- stage regime once: 128 KB, inverse-swizzled source, linear LDS dest
  for (int i = 0; i < 16; ++i) {
    const int cell = i * 512 + t;              // 0..8191
    const int row = cell >> 6, c = cell & 63;
    const int csrc = c ^ (row & 7);
    gll16((const char*)Rn + (rb + row) * 1024 + csrc * 16, ldsb + cell * 16);
  }
  asm volatile("s_waitcnt vmcnt(0)" ::: "memory");
  __syncthreads();

  // B-frag bases: lane covers regime rows wn*64 + fn*32 + (l&31)
  const int row0 = wn * 64 + (l & 31);
  const int row1 = row0 + 32;
  const char* bb0 = ldsb + row0 * 1024;
  const char* bb1 = ldsb + row1 * 1024;
  const int sz0 = row0 & 7, sz1 = row1 & 7;

  // A stream: proto-block pb = ni*16 + wp*4 + fm; addr = (pb*32+kb)*1024 + l*16
  const char* Abase = (const char*)Pk + (long)(wp * 4 * 32) * 1024 + l * 16;

  f32x16 acc[4][2];
  uint32_t k3[2][3];
  float thr[2];
#pragma unroll
  for (int fn = 0; fn < 2; ++fn) {
    thr[fn] = -1e30f;
#pragma unroll
    for (int i = 0; i < 3; ++i) k3[fn][i] = 0u;
  }
  uint4 A0[8], A1[8];   // half-phase ping-pong: 8 frags (fm x 2 ks) each

#define LOADH(BUF, AOFF)                                                       \
  do {                                                                         \
    _Pragma("unroll")                                                          \
    for (int fm_ = 0; fm_ < 4; ++fm_) {                                        \
      _Pragma("unroll")                                                        \
      for (int q_ = 0; q_ < 2; ++q_)                                           \
        BUF[fm_ * 2 + q_] =                                                    \
            *(const uint4*)(Abase + (AOFF) + fm_ * 32768 + q_ * 1024);         \
    }                                                                          \
  } while (0)

#define COMPH(BUF, KB0)                                                        \
  do {                                                                         \
    _Pragma("unroll")                                                          \
    for (int q_ = 0; q_ < 2; ++q_) {                                           \
      const int kb_ = (KB0) + q_;                                              \
      const int g_ = kb_ * 2 + l5;                                             \
      const uint4 b0_ = *(const uint4*)(bb0 + ((g_ ^ sz0) << 4));              \
      const uint4 b1_ = *(const uint4*)(bb1 + ((g_ ^ sz1) << 4));              \
      _Pragma("unroll")                                                        \
      for (int fm_ = 0; fm_ < 4; ++fm_) {                                      \
        acc[fm_][0] = __builtin_amdgcn_mfma_f32_32x32x16_bf16(                 \
            __builtin_bit_cast(s16x8, BUF[fm_ * 2 + q_]),                      \
            __builtin_bit_cast(s16x8, b0_), acc[fm_][0], 0, 0, 0);             \
        acc[fm_][1] = __builtin_amdgcn_mfma_f32_32x32x16_bf16(                 \
            __builtin_bit_cast(s16x8, BUF[fm_ * 2 + q_]),                      \
            __builtin_bit_cast(s16x8, b1_), acc[fm_][1], 0, 0, 0);             \
      }                                                                        \
    }                                                                          \
  } while (0)

  long aoff = 0;           // advances 2048 B per half-phase; ni stride 512 KB
  LOADH(A0, aoff);
  for (int ni = 0; ni < 8; ++ni) {
#pragma unroll
    for (int fm = 0; fm < 4; ++fm)
#pragma unroll
      for (int fn = 0; fn < 2; ++fn)
#pragma unroll
        for (int r = 0; r < 16; ++r) acc[fm][fn][r] = 0.f;

    for (int kp = 0; kp < 8; ++kp) {
      LOADH(A1, aoff + 2048);            // prefetch half 1
      COMPH(A0, kp * 4);                 // compute half 0 (kb = kp*4, +1)
      const long nxt = (kp < 7) ? (aoff + 4096) : (aoff + 4096 + 491520);
      LOADH(A0, nxt);                    // prefetch next phase half 0
      COMPH(A1, kp * 4 + 2);             // compute half 1 (kb = kp*4+2, +3)
      aoff += 4096;
    }
    aoff += 491520;                      // next ni: +512KB total

    // in-register selection: lane owns regime col (l&31) per fn; 16 protos/reg
#pragma unroll
    for (int fm = 0; fm < 4; ++fm) {
      const int pb32 = (ni * 16 + wp * 4 + fm) * 32 + 4 * l5;
#pragma unroll
      for (int fn = 0; fn < 2; ++fn) {
        const f32x16 v = acc[fm][fn];
        float mx = fmaxf(fmaxf(fmaxf(v[0], v[1]), fmaxf(v[2], v[3])),
                         fmaxf(fmaxf(v[4], v[5]), fmaxf(v[6], v[7])));
        mx = fmaxf(mx, fmaxf(fmaxf(fmaxf(v[8], v[9]), fmaxf(v[10], v[11])),
                             fmaxf(fmaxf(v[12], v[13]), fmaxf(v[14], v[15]))));
        if (mx > thr[fn]) {
#pragma unroll
          for (int r = 0; r < 16; ++r) {
            uint32_t kk = packkey(v[r], pb32 + (r & 3) + 8 * (r >> 2));
            uint32_t mx0 = umx(k3[fn][0], kk), mn0 = umn(k3[fn][0], kk);
            k3[fn][0] = mx0; kk = mn0;
            uint32_t mx1 = umx(k3[fn][1], kk), mn1 = umn(k3[fn][1], kk);
            k3[fn][1] = mx1; kk = mn1;
            k3[fn][2] = umx(k3[fn][2], kk);
          }
          thr[fn] = unpackf(k3[fn][2]);
        }
      }
    }
  }
#undef LOADH
#undef COMPH

  // merge lanes l <-> l+32 (same regime rows), write per-wave top lists
  uint32_t cur0[8], cur1[8];
  cur0[0] = k3[0][0]; cur0[1] = k3[0][1]; cur0[2] = k3[0][2];
  cur1[0] = k3[1][0]; cur1[1] = k3[1][1]; cur1[2] = k3[1][2];
#pragma unroll
  for (int i = 3; i < 8; ++i) { cur0[i] = 0u; cur1[i] = 0u; }
  mergeshfl(cur0, 32);
  mergeshfl(cur1, 32);
  if (l < 32) {
    uint32_t* d0 = mrg + ((wn * 64 + l) * 4 + wp) * 8;
    uint32_t* d1 = mrg + ((wn * 64 + 32 + l) * 4 + wp) * 8;
    uint4 a0; a0.x = cur0[0]; a0.y = cur0[1]; a0.z = cur0[2]; a0.w = cur0[3];
    uint4 b0; b0.x = cur0[4]; b0.y = cur0[5]; b0.z = cur0[6]; b0.w = cur0[7];
    uint4 a1; a1.x = cur1[0]; a1.y = cur1[1]; a1.z = cur1[2]; a1.w = cur1[3];
    uint4 b1; b1.x = cur1[4]; b1.y = cur1[5]; b1.z = cur1[6]; b1.w = cur1[7];
    *(uint4*)(d0) = a0; *(uint4*)(d0 + 4) = b0;
    *(uint4*)(d1) = a1; *(uint4*)(d1 + 4) = b1;
  }
  __syncthreads();
  if (t < RPB) {
    const uint32_t* s = mrg + t * 32;
    uint32_t best[8];
#pragma unroll
    for (int i = 0; i < 8; ++i) best[i] = s[i];
#pragma unroll
    for (int j = 8; j < 32; ++j) ins8(best, s[j]);
    uint32_t* d = keys8 + (rb + t) * 8;
    uint4 a; a.x = best[0]; a.y = best[1]; a.z = best[2]; a.w = best[3];
    uint4 b; b.x = best[4]; b.y = best[5]; b.z = best[6]; b.w = best[7];
    *(uint4*)(d) = a; *(uint4*)(d + 4) = b;
  }
}

// ---------------------------------------------------------------------------
// finalize: one wave per row. Margin-gated fp64 rescore, exact top-3 (tie ->
// lower index), softmax(x5), MLP via rproj/cproj, weighted sum.
// ---------------------------------------------------------------------------
__global__ __launch_bounds__(256) void finalize_kernel(
    const float* __restrict__ regime, const float* __restrict__ protoNf,
    const uint32_t* __restrict__ keys8, const float* __restrict__ nrm_r,
    const float* __restrict__ rproj, const float* __restrict__ cproj,
    const float* __restrict__ b1, const float* __restrict__ W2,
    const float* __restrict__ b2, float* __restrict__ out)
{
  __shared__ float rlds[4][512];
  const int t = threadIdx.x, l = t & 63, w = t >> 6;
  const long b = (long)blockIdx.x * 4 + w;

  { // stage fp32-normalized regime row
    const float n = nrm_r[b];
    const float4* gp = (const float4*)(regime + b * BDIM);
    float4 v0 = gp[l], v1 = gp[64 + l];
    v0.x /= n; v0.y /= n; v0.z /= n; v0.w /= n;
    v1.x /= n; v1.y /= n; v1.z /= n; v1.w /= n;
    *(float4*)&rlds[w][4 * l] = v0;
    *(float4*)&rlds[w][256 + 4 * l] = v1;
  }
  __syncthreads();

  const int j = l >> 3;                         // 8 lanes per candidate
  const uint32_t key = keys8[b * 8 + j];
  const int pj = (int)(key & 0xFFFu);
  const float aval = unpackf(key);
  const uint32_t key3 = (uint32_t)__shfl((int)key, 16, 64);   // 3rd-best key
  const float a3 = unpackf(key3);
  const int act = (j < 3) || (aval >= a3 - 4e-3f);  // ~20 sigma of key noise

  double dd = 0.0;
  if (act) {
    const float4* pp = (const float4*)(protoNf + (long)pj * BDIM);
    const float4* rr = (const float4*)&rlds[w][0];
#pragma unroll
    for (int u = 0; u < 16; ++u) {
      const float4 p4 = pp[(l & 7) + 8 * u];
      const float4 r4 = rr[(l & 7) + 8 * u];
      dd = fma((double)p4.x, (double)r4.x, dd);
      dd = fma((double)p4.y, (double)r4.y, dd);
      dd = fma((double)p4.z, (double)r4.z, dd);
      dd = fma((double)p4.w, (double)r4.w, dd);
    }
  }
  dd += __shfl_xor(dd, 1, 64);
  dd += __shfl_xor(dd, 2, 64);
  dd += __shfl_xor(dd, 4, 64);

  double sall[8]; int pall[8];
#pragma unroll
  for (int q = 0; q < 8; ++q) {
    double sq = __shfl(dd, q * 8, 64);
    int aq = __shfl(act, q * 8, 64);
    sall[q] = aq ? sq : -1e300;
    pall[q] = __shfl(pj, q * 8, 64);
  }
  // top-3, tie -> lower prototype index
  double vv[3]; int ppi[3]; unsigned chosen = 0;
#pragma unroll
  for (int r = 0; r < 3; ++r) {
    double bv = -1e301; int bp = 0x7FFFFFFF; int bq = 0;
#pragma unroll
    for (int q = 0; q < 8; ++q) {
      const bool ex = (chosen >> q) & 1u;
      const bool better = !ex && ((sall[q] > bv) || (sall[q] == bv && pall[q] < bp));
      bv = better ? sall[q] : bv;
      bp = better ? pall[q] : bp;
      bq = better ? q : bq;
    }
    vv[r] = bv; ppi[r] = bp; chosen |= 1u << bq;
  }
  const float v0f = (float)vv[0], v1f = (float)vv[1], v2f = (float)vv[2];
  const float e1 = expf(5.f * (v1f - v0f));
  const float e2 = expf(5.f * (v2f - v0f));
  const float winv = 1.f / (1.f + e1 + e2);
  const float w0 = winv, w1 = e1 * winv, w2 = e2 * winv;

  // MLP: h = relu(rproj + cproj[p] + b1); feats = W2 @ h; out = sum wk*feats + b2
  const int hu = l & 31, o = l & 15;
  const float rpv = rproj[b * 32 + hu];
  const float b1v = b1[hu];
  float w2row[32];
#pragma unroll
  for (int hh = 0; hh < 32; ++hh) w2row[hh] = W2[o * 32 + hh];
  float outacc = (l < 16) ? b2[o] : 0.f;        // sum(w)=1 so b2 added once
#pragma unroll
  for (int k = 0; k < 3; ++k) {
    const float cpv = cproj[(long)ppi[k] * 32 + hu];
    const float hval = fmaxf(rpv + cpv + b1v, 0.f);
    float f = 0.f;
#pragma unroll
    for (int hh = 0; hh < 32; ++hh) f = fmaf(w2row[hh], __shfl(hval, hh, 64), f);
    const float wk = (k == 0) ? w0 : ((k == 1) ? w1 : w2);
    outacc = fmaf(wk, f, outacc);
  }
  if (l < 16) out[b * 16 + o] = outacc;
}

// ---------------------------------------------------------------------------
extern "C" void kernel_launch(void* const* d_in, const int* in_sizes, int n_in,
                              void* d_out, int out_size, void* d_ws, size_t ws_size,
                              hipStream_t stream)
{
  (void)in_sizes; (void)n_in; (void)out_size; (void)ws_size;
  const float* regime = (const float*)d_in[0];
  const float* protos = (const float*)d_in[1];
  const float* W1     = (const float*)d_in[2];
  const float* b1     = (const float*)d_in[3];
  const float* W2     = (const float*)d_in[4];
  const float* b2     = (const float*)d_in[5];
  float* out = (float*)d_out;

  char* ws = (char*)d_ws;
  u16*      protoK  = (u16*)ws;      ws += (size_t)NP * BDIM * 2;   //  4 MB (first: prefetch overrun safe)
  u16*      regimeN = (u16*)ws;      ws += (size_t)NB * BDIM * 2;   // 32 MB
  float*    protoNf = (float*)ws;    ws += (size_t)NP * BDIM * 4;   //  8 MB
  float*    nrm_r   = (float*)ws;    ws += (size_t)NB * 4;
  float*    cproj   = (float*)ws;    ws += (size_t)NP * 32 * 4;
  float*    rproj   = (float*)ws;    ws += (size_t)NB * 32 * 4;     //  4 MB
  uint32_t* keys8   = (uint32_t*)ws; ws += (size_t)NB * 8 * 4;      //  1 MB

  hipLaunchKernelGGL(prep_kernel, dim3(NP / 16), dim3(256), 0, stream,
                     protos, W1, 512, 1, protoK, (float*)nullptr, cproj, protoNf);
  hipLaunchKernelGGL(prep_kernel, dim3(NB / 16), dim3(256), 0, stream,
                     regime, W1, 0, 0, regimeN, nrm_r, rproj, (float*)nullptr);
  hipLaunchKernelGGL(topk_kernel, dim3(NB / RPB), dim3(512), 0, stream,
                     regimeN, protoK, keys8);
  hipLaunchKernelGGL(finalize_kernel, dim3(NB / 4), dim3(256), 0, stream,
                     regime, protoNf, keys8, nrm_r, rproj, cproj, b1, W2, b2, out);
}